// Round 7
// baseline (803.898 us; speedup 1.0000x reference)
//
#include <hip/hip_runtime.h>
#include <hip/hip_bf16.h>

#define HF 64
#define EPS 1e-5f
#define SCAN_B 1024

#define BSH 9                    // bucket shift: 512 nodes / bucket
#define BKN (1 << BSH)           // 512 nodes per bucket
#define NBUCK_MAX 256            // >= ceil(N / BKN)
#define PB_T 256                 // passB threads
#define PB_EPT 32                // edges per thread
#define PB_TILE (PB_T * PB_EPT)  // 8192 edges per block

typedef __hip_bfloat16 bf16;

__device__ __forceinline__ unsigned char f32_to_fp8(float v) {
    int p = __builtin_amdgcn_cvt_pk_fp8_f32(v, v, 0, false);
    return (unsigned char)(p & 0xff);
}

// ---- histogram of dst (in-degree, excluding self loop) ----
__global__ void k_hist(int* __restrict__ cnt, const int* __restrict__ dst, int E) {
    int e = blockIdx.x * blockDim.x + threadIdx.x;
    if (e < E) atomicAdd(&cnt[dst[e]], 1);
}

// ---- scan stage 1: per-1024-chunk exclusive scan + chunk totals; also dinv ----
__global__ void k_scan1(const int* __restrict__ cnt, int* __restrict__ chunk_scan,
                        int* __restrict__ bsum, float* __restrict__ dinv, int N) {
    __shared__ int tmp[2][SCAN_B];
    int t = threadIdx.x;
    int gid = blockIdx.x * SCAN_B + t;
    int v = (gid < N) ? cnt[gid] : 0;
    if (gid < N) dinv[gid] = rsqrtf((float)v + 1.0f);
    int pi = 0;
    tmp[0][t] = v;
    __syncthreads();
    for (int off = 1; off < SCAN_B; off <<= 1) {
        int val = tmp[pi][t];
        if (t >= off) val += tmp[pi][t - off];
        tmp[pi ^ 1][t] = val;
        pi ^= 1;
        __syncthreads();
    }
    int inc = tmp[pi][t];
    if (gid < N) chunk_scan[gid] = inc - v;
    if (t == SCAN_B - 1) bsum[blockIdx.x] = inc;
}

// ---- scan stage 2: exclusive scan of chunk totals; writes base[N] = E ----
__global__ void k_scan2(const int* __restrict__ bsum, int* __restrict__ bbase,
                        int* __restrict__ base, int NB, int N) {
    if (threadIdx.x == 0 && blockIdx.x == 0) {
        int acc = 0;
        for (int i = 0; i < NB; ++i) { bbase[i] = acc; acc += bsum[i]; }
        base[N] = acc;   // == E
    }
}

// ---- scan stage 3: base = chunk_scan + bbase ----
__global__ void k_scan3(const int* __restrict__ chunk_scan, const int* __restrict__ bbase,
                        int* __restrict__ base, int N) {
    int gid = blockIdx.x * SCAN_B + threadIdx.x;
    if (gid < N) base[gid] = chunk_scan[gid] + bbase[blockIdx.x];
}

// ---- bucket cursor init: bcur[beta] = base[beta*BKN] ----
__global__ void k_binit(const int* __restrict__ base, int* __restrict__ bcur, int B) {
    int b = blockIdx.x * blockDim.x + threadIdx.x;
    if (b < B) bcur[b] = base[b * BKN];
}

// ---- pass B: block-tiled binning; reserve per-(block,bucket) RUNS, write block-private ----
__global__ __launch_bounds__(PB_T) void k_passB(
    const int* __restrict__ src, const int* __restrict__ dst,
    int* __restrict__ bcur, int* __restrict__ stage, int E, int B) {
    __shared__ int scnt[NBUCK_MAX];
    __shared__ int sgoff[NBUCK_MAX];
    int t = threadIdx.x;
    int tile0 = blockIdx.x * PB_TILE;

    for (int b = t; b < B; b += PB_T) scnt[b] = 0;
    __syncthreads();

    int rec[PB_EPT];
    int bkt[PB_EPT];
#pragma unroll
    for (int k = 0; k < PB_EPT; ++k) {
        int e = tile0 + k * PB_T + t;
        bkt[k] = -1;
        if (e < E) {
            int d = dst[e];
            int s = src[e];
            int b = d >> BSH;
            bkt[k] = b;
            rec[k] = s | ((d & (BKN - 1)) << 17);
            atomicAdd(&scnt[b], 1);
        }
    }
    __syncthreads();

    for (int b = t; b < B; b += PB_T) {
        int c = scnt[b];
        sgoff[b] = c ? atomicAdd(&bcur[b], c) : 0;
        scnt[b] = 0;
    }
    __syncthreads();

#pragma unroll
    for (int k = 0; k < PB_EPT; ++k) {
        if (bkt[k] >= 0) {
            int loc = atomicAdd(&scnt[bkt[k]], 1);
            stage[sgoff[bkt[k]] + loc] = rec[k];
        }
    }
}

// ---- pass C: one block per bucket; scatter staged slice into contiguous CSR rows ----
__global__ __launch_bounds__(512) void k_passC(const int* __restrict__ stage,
                                               const int* __restrict__ base,
                                               int* __restrict__ csr, int N) {
    __shared__ int lcur[BKN];
    int beta = blockIdx.x;
    int n0 = beta * BKN;
    int n1 = n0 + BKN; if (n1 > N) n1 = N;
    int t = threadIdx.x;
    if (t < n1 - n0) lcur[t] = base[n0 + t];
    __syncthreads();
    int rbeg = base[n0], rend = base[n1];
    for (int i = rbeg + t; i < rend; i += 512) {
        int r = stage[i];
        int s = r & 0x1ffff;
        int dl = r >> 17;
        int pos = atomicAdd(&lcur[dl], 1);
        csr[pos] = s;
    }
}

// ---- prescale: xs[n,c] = x[n,c] * dinv[n] ----
__global__ void k_prescale(const float* __restrict__ x, const float* __restrict__ dinv,
                           float* __restrict__ xs, int N5) {
    int i = blockIdx.x * blockDim.x + threadIdx.x;
    if (i < N5) xs[i] = x[i] * dinv[i / 5];
}

// ---- layer 1 fused: dinv[d]*(sum xs[s] + xs[d]) -> @W1 -> BN,ReLU -> hs1 (fp8, pre-scaled) ----
__global__ __launch_bounds__(256) void k_layer1(
    const float* __restrict__ xs, unsigned char* __restrict__ hout,
    const int* __restrict__ csr, const int* __restrict__ basep,
    const float* __restrict__ dinv,
    const float* __restrict__ W1, const float* __restrict__ b,
    const float* __restrict__ g, const float* __restrict__ be,
    const float* __restrict__ rm, const float* __restrict__ rv, int N) {
    __shared__ float sW[5 * HF];
    for (int i = threadIdx.x; i < 5 * HF; i += blockDim.x) sW[i] = W1[i];
    __syncthreads();

    int node = blockIdx.x * (blockDim.x >> 6) + (threadIdx.x >> 6);
    int lane = threadIdx.x & 63;
    if (node >= N) return;

    int j   = __builtin_amdgcn_readfirstlane(basep[node]);
    int end = __builtin_amdgcn_readfirstlane(basep[node + 1]);

    float acc = 0.f;
    if (lane < 5) acc = xs[node * 5 + lane];   // self term
#pragma unroll 4
    for (; j < end; ++j) {
        int s = csr[j];                        // wave-uniform -> scalar load
        if (lane < 5) acc += xs[s * 5 + lane];
    }
    float di = dinv[node];
    acc *= di;

    float out = b[lane];
#pragma unroll
    for (int k = 0; k < 5; ++k) out += __shfl(acc, k, 64) * sW[k * HF + lane];
    out = (out - rm[lane]) * (g[lane] * rsqrtf(rv[lane] + EPS)) + be[lane];
    out = fmaxf(out, 0.f);
    hout[node * HF + lane] = f32_to_fp8(out * di);   // pre-scale for next layer
}

// ---- layers 2/3 fused: fp8 gather (quarter-wave per row), @W, BN, ReLU ----
// SCALE_OUT=1: write fp8 hs = h*dinv. SCALE_OUT=0: write fp32 h (feeds pool).
template <int SCALE_OUT>
__global__ __launch_bounds__(256) void k_layer(
    const unsigned char* __restrict__ hs8, void* __restrict__ hout_v,
    const int* __restrict__ csr, const int* __restrict__ basep,
    const float* __restrict__ dinv,
    const float* __restrict__ W, const float* __restrict__ b,
    const float* __restrict__ g, const float* __restrict__ be,
    const float* __restrict__ rm, const float* __restrict__ rv, int N) {
    __shared__ float sW[HF * HF];
    for (int i = threadIdx.x; i < HF * HF; i += blockDim.x) sW[i] = W[i];
    __syncthreads();

    int node = blockIdx.x * (blockDim.x >> 6) + (threadIdx.x >> 6);
    int lane = threadIdx.x & 63;
    if (node >= N) return;

    int q = lane >> 4;          // row group 0..3
    int l = lane & 15;          // 4-feature slot within row

    int j   = __builtin_amdgcn_readfirstlane(basep[node]);
    int end = __builtin_amdgcn_readfirstlane(basep[node + 1]);

    float a0 = 0.f, a1 = 0.f, a2 = 0.f, a3 = 0.f;
#pragma unroll 2
    for (; j < end; j += 4) {
        int idx = j + q;
        if (idx < end) {
            int s = csr[idx];   // 16 lanes/group share one address
            unsigned u = *(const unsigned*)(hs8 + (size_t)s * HF + l * 4);
            a0 += __builtin_amdgcn_cvt_f32_fp8(u, 0);
            a1 += __builtin_amdgcn_cvt_f32_fp8(u, 1);
            a2 += __builtin_amdgcn_cvt_f32_fp8(u, 2);
            a3 += __builtin_amdgcn_cvt_f32_fp8(u, 3);
        }
    }
    // reduce the 4 row-groups (features are replicated across groups)
    a0 += __shfl_xor(a0, 16, 64); a0 += __shfl_xor(a0, 32, 64);
    a1 += __shfl_xor(a1, 16, 64); a1 += __shfl_xor(a1, 32, 64);
    a2 += __shfl_xor(a2, 16, 64); a2 += __shfl_xor(a2, 32, 64);
    a3 += __shfl_xor(a3, 16, 64); a3 += __shfl_xor(a3, 32, 64);

    // self term (same value in all 4 replicas)
    {
        unsigned u = *(const unsigned*)(hs8 + (size_t)node * HF + l * 4);
        a0 += __builtin_amdgcn_cvt_f32_fp8(u, 0);
        a1 += __builtin_amdgcn_cvt_f32_fp8(u, 1);
        a2 += __builtin_amdgcn_cvt_f32_fp8(u, 2);
        a3 += __builtin_amdgcn_cvt_f32_fp8(u, 3);
    }
    float di = dinv[node];
    a0 *= di; a1 *= di; a2 *= di; a3 *= di;

    // matmul: agg value for k = l'*4+i lives in lane l' (group 0) slot i
    float out = b[lane];
#pragma unroll
    for (int k = 0; k < HF; k += 4) {
        int sl = k >> 2;
        out += __shfl(a0, sl, 64) * sW[(k + 0) * HF + lane];
        out += __shfl(a1, sl, 64) * sW[(k + 1) * HF + lane];
        out += __shfl(a2, sl, 64) * sW[(k + 2) * HF + lane];
        out += __shfl(a3, sl, 64) * sW[(k + 3) * HF + lane];
    }
    out = (out - rm[lane]) * (g[lane] * rsqrtf(rv[lane] + EPS)) + be[lane];
    out = fmaxf(out, 0.f);
    if (SCALE_OUT) {
        ((unsigned char*)hout_v)[(size_t)node * HF + lane] = f32_to_fp8(out * di);
    } else {
        ((float*)hout_v)[(size_t)node * HF + lane] = out;
    }
}

// ---- per-graph mean-pool + FC(64->32) relu + FC(32->2) sigmoid ----
__global__ void k_pool_fc(const float* __restrict__ h, const int* __restrict__ batch,
                          const float* __restrict__ Wf1, const float* __restrict__ bf1,
                          const float* __restrict__ Wf2, const float* __restrict__ bf2,
                          float* __restrict__ out, int N) {
    int g = blockIdx.x;
    int t = threadIdx.x;
    int f = t & 63, q = t >> 6;

    int lo = 0, hi = N;
    while (lo < hi) { int mid = (lo + hi) >> 1; if (batch[mid] < g) lo = mid + 1; else hi = mid; }
    int start = lo;
    hi = N;
    while (lo < hi) { int mid = (lo + hi) >> 1; if (batch[mid] < g + 1) lo = mid + 1; else hi = mid; }
    int end = lo;

    float sum = 0.f;
    for (int n = start + q; n < end; n += 4) sum += h[n * HF + f];

    __shared__ float red[4][HF];
    __shared__ float sp[HF];
    __shared__ float sh[32];
    red[q][f] = sum;
    __syncthreads();
    if (q == 0) {
        float s = red[0][f] + red[1][f] + red[2][f] + red[3][f];
        float cntf = (float)(end - start);
        sp[f] = s / fmaxf(cntf, 1.0f);
    }
    __syncthreads();
    if (t < 32) {
        float a = bf1[t];
#pragma unroll
        for (int k = 0; k < HF; ++k) a += sp[k] * Wf1[k * 32 + t];
        sh[t] = fmaxf(a, 0.f);
    }
    __syncthreads();
    if (t < 2) {
        float a = bf2[t];
#pragma unroll
        for (int k = 0; k < 32; ++k) a += sh[k] * Wf2[k * 2 + t];
        out[g * 2 + t] = 1.f / (1.f + expf(-a));
    }
}

extern "C" void kernel_launch(void* const* d_in, const int* in_sizes, int n_in,
                              void* d_out, int out_size, void* d_ws, size_t ws_size,
                              hipStream_t stream) {
    const float* x     = (const float*)d_in[0];
    const int*   ei    = (const int*)d_in[1];
    const int*   batch = (const int*)d_in[2];
    const float* W1 = (const float*)d_in[3];
    const float* b1 = (const float*)d_in[4];
    const float* g1 = (const float*)d_in[5];
    const float* be1 = (const float*)d_in[6];
    const float* rm1 = (const float*)d_in[7];
    const float* rv1 = (const float*)d_in[8];
    const float* W2 = (const float*)d_in[9];
    const float* b2 = (const float*)d_in[10];
    const float* g2 = (const float*)d_in[11];
    const float* be2 = (const float*)d_in[12];
    const float* rm2 = (const float*)d_in[13];
    const float* rv2 = (const float*)d_in[14];
    const float* W3 = (const float*)d_in[15];
    const float* b3 = (const float*)d_in[16];
    const float* g3 = (const float*)d_in[17];
    const float* be3 = (const float*)d_in[18];
    const float* rm3 = (const float*)d_in[19];
    const float* rv3 = (const float*)d_in[20];
    const float* Wf1 = (const float*)d_in[21];
    const float* bf1 = (const float*)d_in[22];
    const float* Wf2 = (const float*)d_in[23];
    const float* bf2 = (const float*)d_in[24];
    float* out = (float*)d_out;

    const int N = in_sizes[2];            // 100000
    const int E = in_sizes[1] / 2;        // 3200000
    const int G = out_size / 2;           // 256
    const int B = (N + BKN - 1) / BKN;    // buckets (196)

    char* ws = (char*)d_ws;
    size_t off = 0;
    auto alloc = [&](size_t bytes) {
        char* p = ws + off;
        off += (bytes + 255) & ~(size_t)255;
        return p;
    };
    float*         H3       = (float*)alloc((size_t)N * HF * sizeof(float));
    unsigned char* HS1      = (unsigned char*)alloc((size_t)N * HF);
    unsigned char* HS2      = (unsigned char*)alloc((size_t)N * HF);
    float*         xs       = (float*)alloc((size_t)N * 5 * sizeof(float));
    float*         dinv     = (float*)alloc((size_t)N * sizeof(float));
    int*           cnt      = (int*)  alloc((size_t)N * sizeof(int));
    int*           chunk_sc = (int*)  alloc((size_t)N * sizeof(int));
    int*           base     = (int*)  alloc(((size_t)N + 1) * sizeof(int));
    int*           bcur     = (int*)  alloc((size_t)NBUCK_MAX * sizeof(int));
    int*           bsum     = (int*)  alloc(256 * sizeof(int));
    int*           bbase    = (int*)  alloc(256 * sizeof(int));
    int*           csr      = (int*)  alloc((size_t)E * sizeof(int));
    int*           stage    = (int*)H3;   // alias: consumed (passC) before H3 written (layer 3)

    const int* src = ei;
    const int* dst = ei + E;

    const int BT = 256;
    int gE  = (E + BT - 1) / BT;
    int NB  = (N + SCAN_B - 1) / SCAN_B;
    int gW  = (N + 3) / 4;
    int gP  = (N * 5 + BT - 1) / BT;
    int gPB = (E + PB_TILE - 1) / PB_TILE;

    // ---- CSR build ----
    hipMemsetAsync(cnt, 0, (size_t)N * sizeof(int), stream);
    k_hist<<<gE, BT, 0, stream>>>(cnt, dst, E);
    k_scan1<<<NB, SCAN_B, 0, stream>>>(cnt, chunk_sc, bsum, dinv, N);
    k_scan2<<<1, 64, 0, stream>>>(bsum, bbase, base, NB, N);
    k_scan3<<<NB, SCAN_B, 0, stream>>>(chunk_sc, bbase, base, N);
    k_binit<<<1, 256, 0, stream>>>(base, bcur, B);
    k_passB<<<gPB, PB_T, 0, stream>>>(src, dst, bcur, stage, E, B);
    k_passC<<<B, 512, 0, stream>>>(stage, base, csr, N);
    k_prescale<<<gP, BT, 0, stream>>>(x, dinv, xs, N * 5);

    // ---- fused layers ----
    k_layer1<<<gW, BT, 0, stream>>>(xs, HS1, csr, base, dinv,
                                    W1, b1, g1, be1, rm1, rv1, N);
    k_layer<1><<<gW, BT, 0, stream>>>(HS1, HS2, csr, base, dinv,
                                      W2, b2, g2, be2, rm2, rv2, N);
    k_layer<0><<<gW, BT, 0, stream>>>(HS2, H3, csr, base, dinv,
                                      W3, b3, g3, be3, rm3, rv3, N);

    // ---- pool + MLP head ----
    k_pool_fc<<<G, BT, 0, stream>>>(H3, batch, Wf1, bf1, Wf2, bf2, out, N);
}

// Round 8
// 788.271 us; speedup vs baseline: 1.0198x; 1.0198x over previous
//
#include <hip/hip_runtime.h>
#include <hip/hip_bf16.h>

#define HF 64
#define EPS 1e-5f
#define SCAN_B 1024

#define BSH 9                    // bucket shift: 512 nodes / bucket
#define BKN (1 << BSH)           // 512 nodes per bucket
#define NBUCK_MAX 256            // >= ceil(N / BKN)
#define PB_T 256                 // passB threads
#define PB_EPT 32                // edges per thread
#define PB_TILE (PB_T * PB_EPT)  // 8192 edges per block

typedef __hip_bfloat16 bf16;

__device__ __forceinline__ unsigned char f32_to_fp8(float v) {
    int p = __builtin_amdgcn_cvt_pk_fp8_f32(v, v, 0, false);
    return (unsigned char)(p & 0xff);
}

// ---- histogram of dst (in-degree, excluding self loop) ----
__global__ void k_hist(int* __restrict__ cnt, const int* __restrict__ dst, int E) {
    int e = blockIdx.x * blockDim.x + threadIdx.x;
    if (e < E) atomicAdd(&cnt[dst[e]], 1);
}

// ---- scan stage 1: per-1024-chunk exclusive scan + chunk totals; also dinv ----
__global__ void k_scan1(const int* __restrict__ cnt, int* __restrict__ chunk_scan,
                        int* __restrict__ bsum, float* __restrict__ dinv, int N) {
    __shared__ int tmp[2][SCAN_B];
    int t = threadIdx.x;
    int gid = blockIdx.x * SCAN_B + t;
    int v = (gid < N) ? cnt[gid] : 0;
    if (gid < N) dinv[gid] = rsqrtf((float)v + 1.0f);
    int pi = 0;
    tmp[0][t] = v;
    __syncthreads();
    for (int off = 1; off < SCAN_B; off <<= 1) {
        int val = tmp[pi][t];
        if (t >= off) val += tmp[pi][t - off];
        tmp[pi ^ 1][t] = val;
        pi ^= 1;
        __syncthreads();
    }
    int inc = tmp[pi][t];
    if (gid < N) chunk_scan[gid] = inc - v;
    if (t == SCAN_B - 1) bsum[blockIdx.x] = inc;
}

// ---- scan stage 2: exclusive scan of chunk totals; writes base[N] = E ----
__global__ void k_scan2(const int* __restrict__ bsum, int* __restrict__ bbase,
                        int* __restrict__ base, int NB, int N) {
    if (threadIdx.x == 0 && blockIdx.x == 0) {
        int acc = 0;
        for (int i = 0; i < NB; ++i) { bbase[i] = acc; acc += bsum[i]; }
        base[N] = acc;   // == E
    }
}

// ---- scan stage 3: base = chunk_scan + bbase ----
__global__ void k_scan3(const int* __restrict__ chunk_scan, const int* __restrict__ bbase,
                        int* __restrict__ base, int N) {
    int gid = blockIdx.x * SCAN_B + threadIdx.x;
    if (gid < N) base[gid] = chunk_scan[gid] + bbase[blockIdx.x];
}

// ---- bucket cursor init: bcur[beta] = base[beta*BKN] ----
__global__ void k_binit(const int* __restrict__ base, int* __restrict__ bcur, int B) {
    int b = blockIdx.x * blockDim.x + threadIdx.x;
    if (b < B) bcur[b] = base[b * BKN];
}

// ---- pass B: block-tiled binning; reserve per-(block,bucket) RUNS, write block-private ----
__global__ __launch_bounds__(PB_T) void k_passB(
    const int* __restrict__ src, const int* __restrict__ dst,
    int* __restrict__ bcur, int* __restrict__ stage, int E, int B) {
    __shared__ int scnt[NBUCK_MAX];
    __shared__ int sgoff[NBUCK_MAX];
    int t = threadIdx.x;
    int tile0 = blockIdx.x * PB_TILE;

    for (int b = t; b < B; b += PB_T) scnt[b] = 0;
    __syncthreads();

    int rec[PB_EPT];
    int bkt[PB_EPT];
#pragma unroll
    for (int k = 0; k < PB_EPT; ++k) {
        int e = tile0 + k * PB_T + t;
        bkt[k] = -1;
        if (e < E) {
            int d = dst[e];
            int s = src[e];
            int b = d >> BSH;
            bkt[k] = b;
            rec[k] = s | ((d & (BKN - 1)) << 17);
            atomicAdd(&scnt[b], 1);
        }
    }
    __syncthreads();

    for (int b = t; b < B; b += PB_T) {
        int c = scnt[b];
        sgoff[b] = c ? atomicAdd(&bcur[b], c) : 0;
        scnt[b] = 0;
    }
    __syncthreads();

#pragma unroll
    for (int k = 0; k < PB_EPT; ++k) {
        if (bkt[k] >= 0) {
            int loc = atomicAdd(&scnt[bkt[k]], 1);
            stage[sgoff[bkt[k]] + loc] = rec[k];
        }
    }
}

// ---- pass C: one block per bucket; scatter staged slice into contiguous CSR rows ----
__global__ __launch_bounds__(512) void k_passC(const int* __restrict__ stage,
                                               const int* __restrict__ base,
                                               int* __restrict__ csr, int N) {
    __shared__ int lcur[BKN];
    int beta = blockIdx.x;
    int n0 = beta * BKN;
    int n1 = n0 + BKN; if (n1 > N) n1 = N;
    int t = threadIdx.x;
    if (t < n1 - n0) lcur[t] = base[n0 + t];
    __syncthreads();
    int rbeg = base[n0], rend = base[n1];
    for (int i = rbeg + t; i < rend; i += 512) {
        int r = stage[i];
        int s = r & 0x1ffff;
        int dl = r >> 17;
        int pos = atomicAdd(&lcur[dl], 1);
        csr[pos] = s;
    }
}

// ---- prescale: xs[n,c] = x[n,c] * dinv[n] ----
__global__ void k_prescale(const float* __restrict__ x, const float* __restrict__ dinv,
                           float* __restrict__ xs, int N5) {
    int i = blockIdx.x * blockDim.x + threadIdx.x;
    if (i < N5) xs[i] = x[i] * dinv[i / 5];
}

// ---- layer 1 fused: dinv[d]*(sum xs[s] + xs[d]) -> @W1' (BN-folded) -> ReLU -> hs1 (fp8) ----
__global__ __launch_bounds__(256) void k_layer1(
    const float* __restrict__ xs, unsigned char* __restrict__ hout,
    const int* __restrict__ csr, const int* __restrict__ basep,
    const float* __restrict__ dinv,
    const float* __restrict__ W1, const float* __restrict__ b,
    const float* __restrict__ g, const float* __restrict__ be,
    const float* __restrict__ rm, const float* __restrict__ rv, int N) {
    __shared__ float sW[5 * HF];
    __shared__ float sB[HF];
    for (int i = threadIdx.x; i < 5 * HF; i += blockDim.x) {
        int f = i & (HF - 1);
        sW[i] = W1[i] * (g[f] * rsqrtf(rv[f] + EPS));
    }
    if (threadIdx.x < HF) {
        int f = threadIdx.x;
        float scale = g[f] * rsqrtf(rv[f] + EPS);
        sB[f] = (b[f] - rm[f]) * scale + be[f];
    }
    __syncthreads();

    int node = blockIdx.x * (blockDim.x >> 6) + (threadIdx.x >> 6);
    int lane = threadIdx.x & 63;
    if (node >= N) return;

    int j   = __builtin_amdgcn_readfirstlane(basep[node]);
    int end = __builtin_amdgcn_readfirstlane(basep[node + 1]);

    float acc = 0.f;
    if (lane < 5) acc = xs[node * 5 + lane];   // self term
#pragma unroll 4
    for (; j < end; ++j) {
        int s = csr[j];                        // wave-uniform -> scalar load
        if (lane < 5) acc += xs[s * 5 + lane];
    }
    float di = dinv[node];
    acc *= di;

    float out = sB[lane];
#pragma unroll
    for (int k = 0; k < 5; ++k) out += __shfl(acc, k, 64) * sW[k * HF + lane];
    out = fmaxf(out, 0.f);
    hout[node * HF + lane] = f32_to_fp8(out * di);   // pre-scale for next layer
}

// ---- layers 2/3 fused: fp8 gather (1 byte/lane, 1 line/edge), @W' (BN-folded), ReLU ----
// SCALE_OUT=1: write fp8 hs = h*dinv. SCALE_OUT=0: write fp32 h (feeds pool).
template <int SCALE_OUT>
__global__ __launch_bounds__(256) void k_layer(
    const unsigned char* __restrict__ hs8, void* __restrict__ hout_v,
    const int* __restrict__ csr, const int* __restrict__ basep,
    const float* __restrict__ dinv,
    const float* __restrict__ W, const float* __restrict__ b,
    const float* __restrict__ g, const float* __restrict__ be,
    const float* __restrict__ rm, const float* __restrict__ rv, int N) {
    __shared__ float sW[HF * HF];
    __shared__ float sB[HF];
    for (int i = threadIdx.x; i < HF * HF; i += blockDim.x) {
        int f = i & (HF - 1);
        sW[i] = W[i] * (g[f] * rsqrtf(rv[f] + EPS));
    }
    if (threadIdx.x < HF) {
        int f = threadIdx.x;
        float scale = g[f] * rsqrtf(rv[f] + EPS);
        sB[f] = (b[f] - rm[f]) * scale + be[f];
    }
    __syncthreads();

    int node = blockIdx.x * (blockDim.x >> 6) + (threadIdx.x >> 6);
    int lane = threadIdx.x & 63;
    if (node >= N) return;

    int j   = __builtin_amdgcn_readfirstlane(basep[node]);
    int end = __builtin_amdgcn_readfirstlane(basep[node + 1]);

    const unsigned char* col = hs8 + lane;   // lane's feature column

    // self term (already *dinv[src])
    float acc = __builtin_amdgcn_cvt_f32_fp8((unsigned)col[(size_t)node * HF], 0);
#pragma unroll 4
    for (; j < end; ++j) {
        int s = csr[j];                       // wave-uniform -> scalar load
        unsigned u = col[(size_t)s * HF];     // 1 B/lane: 64 lanes = exactly 1 line
        acc += __builtin_amdgcn_cvt_f32_fp8(u, 0);
    }
    float di = dinv[node];
    acc *= di;

    float out = sB[lane];
#pragma unroll 8
    for (int k = 0; k < HF; ++k) out += __shfl(acc, k, 64) * sW[k * HF + lane];
    out = fmaxf(out, 0.f);
    if (SCALE_OUT) {
        ((unsigned char*)hout_v)[(size_t)node * HF + lane] = f32_to_fp8(out * di);
    } else {
        ((float*)hout_v)[(size_t)node * HF + lane] = out;
    }
}

// ---- per-graph mean-pool + FC(64->32) relu + FC(32->2) sigmoid ----
__global__ void k_pool_fc(const float* __restrict__ h, const int* __restrict__ batch,
                          const float* __restrict__ Wf1, const float* __restrict__ bf1,
                          const float* __restrict__ Wf2, const float* __restrict__ bf2,
                          float* __restrict__ out, int N) {
    int g = blockIdx.x;
    int t = threadIdx.x;
    int f = t & 63, q = t >> 6;

    int lo = 0, hi = N;
    while (lo < hi) { int mid = (lo + hi) >> 1; if (batch[mid] < g) lo = mid + 1; else hi = mid; }
    int start = lo;
    hi = N;
    while (lo < hi) { int mid = (lo + hi) >> 1; if (batch[mid] < g + 1) lo = mid + 1; else hi = mid; }
    int end = lo;

    float sum = 0.f;
    for (int n = start + q; n < end; n += 4) sum += h[n * HF + f];

    __shared__ float red[4][HF];
    __shared__ float sp[HF];
    __shared__ float sh[32];
    red[q][f] = sum;
    __syncthreads();
    if (q == 0) {
        float s = red[0][f] + red[1][f] + red[2][f] + red[3][f];
        float cntf = (float)(end - start);
        sp[f] = s / fmaxf(cntf, 1.0f);
    }
    __syncthreads();
    if (t < 32) {
        float a = bf1[t];
#pragma unroll
        for (int k = 0; k < HF; ++k) a += sp[k] * Wf1[k * 32 + t];
        sh[t] = fmaxf(a, 0.f);
    }
    __syncthreads();
    if (t < 2) {
        float a = bf2[t];
#pragma unroll
        for (int k = 0; k < 32; ++k) a += sh[k] * Wf2[k * 2 + t];
        out[g * 2 + t] = 1.f / (1.f + expf(-a));
    }
}

extern "C" void kernel_launch(void* const* d_in, const int* in_sizes, int n_in,
                              void* d_out, int out_size, void* d_ws, size_t ws_size,
                              hipStream_t stream) {
    const float* x     = (const float*)d_in[0];
    const int*   ei    = (const int*)d_in[1];
    const int*   batch = (const int*)d_in[2];
    const float* W1 = (const float*)d_in[3];
    const float* b1 = (const float*)d_in[4];
    const float* g1 = (const float*)d_in[5];
    const float* be1 = (const float*)d_in[6];
    const float* rm1 = (const float*)d_in[7];
    const float* rv1 = (const float*)d_in[8];
    const float* W2 = (const float*)d_in[9];
    const float* b2 = (const float*)d_in[10];
    const float* g2 = (const float*)d_in[11];
    const float* be2 = (const float*)d_in[12];
    const float* rm2 = (const float*)d_in[13];
    const float* rv2 = (const float*)d_in[14];
    const float* W3 = (const float*)d_in[15];
    const float* b3 = (const float*)d_in[16];
    const float* g3 = (const float*)d_in[17];
    const float* be3 = (const float*)d_in[18];
    const float* rm3 = (const float*)d_in[19];
    const float* rv3 = (const float*)d_in[20];
    const float* Wf1 = (const float*)d_in[21];
    const float* bf1 = (const float*)d_in[22];
    const float* Wf2 = (const float*)d_in[23];
    const float* bf2 = (const float*)d_in[24];
    float* out = (float*)d_out;

    const int N = in_sizes[2];            // 100000
    const int E = in_sizes[1] / 2;        // 3200000
    const int G = out_size / 2;           // 256
    const int B = (N + BKN - 1) / BKN;    // buckets (196)

    char* ws = (char*)d_ws;
    size_t off = 0;
    auto alloc = [&](size_t bytes) {
        char* p = ws + off;
        off += (bytes + 255) & ~(size_t)255;
        return p;
    };
    float*         H3       = (float*)alloc((size_t)N * HF * sizeof(float));
    unsigned char* HS1      = (unsigned char*)alloc((size_t)N * HF);
    unsigned char* HS2      = (unsigned char*)alloc((size_t)N * HF);
    float*         xs       = (float*)alloc((size_t)N * 5 * sizeof(float));
    float*         dinv     = (float*)alloc((size_t)N * sizeof(float));
    int*           cnt      = (int*)  alloc((size_t)N * sizeof(int));
    int*           chunk_sc = (int*)  alloc((size_t)N * sizeof(int));
    int*           base     = (int*)  alloc(((size_t)N + 1) * sizeof(int));
    int*           bcur     = (int*)  alloc((size_t)NBUCK_MAX * sizeof(int));
    int*           bsum     = (int*)  alloc(256 * sizeof(int));
    int*           bbase    = (int*)  alloc(256 * sizeof(int));
    int*           csr      = (int*)  alloc((size_t)E * sizeof(int));
    int*           stage    = (int*)H3;   // alias: consumed (passC) before H3 written (layer 3)

    const int* src = ei;
    const int* dst = ei + E;

    const int BT = 256;
    int gE  = (E + BT - 1) / BT;
    int NB  = (N + SCAN_B - 1) / SCAN_B;
    int gW  = (N + 3) / 4;
    int gP  = (N * 5 + BT - 1) / BT;
    int gPB = (E + PB_TILE - 1) / PB_TILE;

    // ---- CSR build ----
    hipMemsetAsync(cnt, 0, (size_t)N * sizeof(int), stream);
    k_hist<<<gE, BT, 0, stream>>>(cnt, dst, E);
    k_scan1<<<NB, SCAN_B, 0, stream>>>(cnt, chunk_sc, bsum, dinv, N);
    k_scan2<<<1, 64, 0, stream>>>(bsum, bbase, base, NB, N);
    k_scan3<<<NB, SCAN_B, 0, stream>>>(chunk_sc, bbase, base, N);
    k_binit<<<1, 256, 0, stream>>>(base, bcur, B);
    k_passB<<<gPB, PB_T, 0, stream>>>(src, dst, bcur, stage, E, B);
    k_passC<<<B, 512, 0, stream>>>(stage, base, csr, N);
    k_prescale<<<gP, BT, 0, stream>>>(x, dinv, xs, N * 5);

    // ---- fused layers ----
    k_layer1<<<gW, BT, 0, stream>>>(xs, HS1, csr, base, dinv,
                                    W1, b1, g1, be1, rm1, rv1, N);
    k_layer<1><<<gW, BT, 0, stream>>>(HS1, HS2, csr, base, dinv,
                                      W2, b2, g2, be2, rm2, rv2, N);
    k_layer<0><<<gW, BT, 0, stream>>>(HS2, H3, csr, base, dinv,
                                      W3, b3, g3, be3, rm3, rv3, N);

    // ---- pool + MLP head ----
    k_pool_fc<<<G, BT, 0, stream>>>(H3, batch, Wf1, bf1, Wf2, bf2, out, N);
}

// Round 9
// 716.568 us; speedup vs baseline: 1.1219x; 1.1001x over previous
//
#include <hip/hip_runtime.h>
#include <hip/hip_bf16.h>

#define HF 64
#define EPS 1e-5f
#define SCAN_B 1024

#define BSH 9                    // bucket shift: 512 nodes / bucket
#define BKN (1 << BSH)           // 512 nodes per bucket
#define NBUCK_MAX 256            // >= ceil(N / BKN)
#define PB_T 256                 // passB threads
#define PB_EPT 32                // edges per thread
#define PB_TILE (PB_T * PB_EPT)  // 8192 edges per block

typedef __hip_bfloat16 bf16;

__device__ __forceinline__ unsigned char f32_to_fp8(float v) {
    int p = __builtin_amdgcn_cvt_pk_fp8_f32(v, v, 0, false);
    return (unsigned char)(p & 0xff);
}

// ---- histogram of dst (in-degree, excluding self loop) ----
__global__ void k_hist(int* __restrict__ cnt, const int* __restrict__ dst, int E) {
    int e = blockIdx.x * blockDim.x + threadIdx.x;
    if (e < E) atomicAdd(&cnt[dst[e]], 1);
}

// ---- scan stage 1: per-1024-chunk exclusive scan + chunk totals; also dinv ----
__global__ void k_scan1(const int* __restrict__ cnt, int* __restrict__ chunk_scan,
                        int* __restrict__ bsum, float* __restrict__ dinv, int N) {
    __shared__ int tmp[2][SCAN_B];
    int t = threadIdx.x;
    int gid = blockIdx.x * SCAN_B + t;
    int v = (gid < N) ? cnt[gid] : 0;
    if (gid < N) dinv[gid] = rsqrtf((float)v + 1.0f);
    int pi = 0;
    tmp[0][t] = v;
    __syncthreads();
    for (int off = 1; off < SCAN_B; off <<= 1) {
        int val = tmp[pi][t];
        if (t >= off) val += tmp[pi][t - off];
        tmp[pi ^ 1][t] = val;
        pi ^= 1;
        __syncthreads();
    }
    int inc = tmp[pi][t];
    if (gid < N) chunk_scan[gid] = inc - v;
    if (t == SCAN_B - 1) bsum[blockIdx.x] = inc;
}

// ---- scan stage 2: exclusive scan of chunk totals; writes base[N] = E ----
__global__ void k_scan2(const int* __restrict__ bsum, int* __restrict__ bbase,
                        int* __restrict__ base, int NB, int N) {
    if (threadIdx.x == 0 && blockIdx.x == 0) {
        int acc = 0;
        for (int i = 0; i < NB; ++i) { bbase[i] = acc; acc += bsum[i]; }
        base[N] = acc;   // == E
    }
}

// ---- scan stage 3: base = chunk_scan + bbase ----
__global__ void k_scan3(const int* __restrict__ chunk_scan, const int* __restrict__ bbase,
                        int* __restrict__ base, int N) {
    int gid = blockIdx.x * SCAN_B + threadIdx.x;
    if (gid < N) base[gid] = chunk_scan[gid] + bbase[blockIdx.x];
}

// ---- bucket cursor init: bcur[beta] = base[beta*BKN] ----
__global__ void k_binit(const int* __restrict__ base, int* __restrict__ bcur, int B) {
    int b = blockIdx.x * blockDim.x + threadIdx.x;
    if (b < B) bcur[b] = base[b * BKN];
}

// ---- pass B: block-tiled binning; reserve per-(block,bucket) RUNS, write block-private ----
__global__ __launch_bounds__(PB_T) void k_passB(
    const int* __restrict__ src, const int* __restrict__ dst,
    int* __restrict__ bcur, int* __restrict__ stage, int E, int B) {
    __shared__ int scnt[NBUCK_MAX];
    __shared__ int sgoff[NBUCK_MAX];
    int t = threadIdx.x;
    int tile0 = blockIdx.x * PB_TILE;

    for (int b = t; b < B; b += PB_T) scnt[b] = 0;
    __syncthreads();

    int rec[PB_EPT];
    int bkt[PB_EPT];
#pragma unroll
    for (int k = 0; k < PB_EPT; ++k) {
        int e = tile0 + k * PB_T + t;
        bkt[k] = -1;
        if (e < E) {
            int d = dst[e];
            int s = src[e];
            int b = d >> BSH;
            bkt[k] = b;
            rec[k] = s | ((d & (BKN - 1)) << 17);
            atomicAdd(&scnt[b], 1);
        }
    }
    __syncthreads();

    for (int b = t; b < B; b += PB_T) {
        int c = scnt[b];
        sgoff[b] = c ? atomicAdd(&bcur[b], c) : 0;
        scnt[b] = 0;
    }
    __syncthreads();

#pragma unroll
    for (int k = 0; k < PB_EPT; ++k) {
        if (bkt[k] >= 0) {
            int loc = atomicAdd(&scnt[bkt[k]], 1);
            stage[sgoff[bkt[k]] + loc] = rec[k];
        }
    }
}

// ---- pass C: one block per bucket; scatter staged slice into contiguous CSR rows ----
__global__ __launch_bounds__(512) void k_passC(const int* __restrict__ stage,
                                               const int* __restrict__ base,
                                               int* __restrict__ csr, int N) {
    __shared__ int lcur[BKN];
    int beta = blockIdx.x;
    int n0 = beta * BKN;
    int n1 = n0 + BKN; if (n1 > N) n1 = N;
    int t = threadIdx.x;
    if (t < n1 - n0) lcur[t] = base[n0 + t];
    __syncthreads();
    int rbeg = base[n0], rend = base[n1];
    for (int i = rbeg + t; i < rend; i += 512) {
        int r = stage[i];
        int s = r & 0x1ffff;
        int dl = r >> 17;
        int pos = atomicAdd(&lcur[dl], 1);
        csr[pos] = s;
    }
}

// ---- prescale: xs[n,c] = x[n,c] * dinv[n] ----
__global__ void k_prescale(const float* __restrict__ x, const float* __restrict__ dinv,
                           float* __restrict__ xs, int N5) {
    int i = blockIdx.x * blockDim.x + threadIdx.x;
    if (i < N5) xs[i] = x[i] * dinv[i / 5];
}

// ---- layer 1 fused: dinv[d]*(sum xs[s] + xs[d]) -> @W1' (BN-folded) -> ReLU -> hs1 (fp8) ----
__global__ __launch_bounds__(256) void k_layer1(
    const float* __restrict__ xs, unsigned char* __restrict__ hout,
    const int* __restrict__ csr, const int* __restrict__ basep,
    const float* __restrict__ dinv,
    const float* __restrict__ W1, const float* __restrict__ b,
    const float* __restrict__ g, const float* __restrict__ be,
    const float* __restrict__ rm, const float* __restrict__ rv, int N) {
    __shared__ float sW[5 * HF];
    __shared__ float sB[HF];
    for (int i = threadIdx.x; i < 5 * HF; i += blockDim.x) {
        int f = i & (HF - 1);
        sW[i] = W1[i] * (g[f] * rsqrtf(rv[f] + EPS));
    }
    if (threadIdx.x < HF) {
        int f = threadIdx.x;
        float scale = g[f] * rsqrtf(rv[f] + EPS);
        sB[f] = (b[f] - rm[f]) * scale + be[f];
    }
    __syncthreads();

    int node = blockIdx.x * (blockDim.x >> 6) + (threadIdx.x >> 6);
    int lane = threadIdx.x & 63;
    if (node >= N) return;

    int j   = __builtin_amdgcn_readfirstlane(basep[node]);
    int end = __builtin_amdgcn_readfirstlane(basep[node + 1]);

    float a0 = 0.f, a1 = 0.f, a2 = 0.f, a3 = 0.f;
    if (lane < 5) a0 = xs[node * 5 + lane];   // self term
    // 8-wide MLP: indices first (merged s_loads), then 8 independent gathers
    for (; j + 8 <= end; j += 8) {
        int s0 = csr[j+0], s1 = csr[j+1], s2 = csr[j+2], s3 = csr[j+3];
        int s4 = csr[j+4], s5 = csr[j+5], s6 = csr[j+6], s7 = csr[j+7];
        if (lane < 5) {
            float v0 = xs[s0 * 5 + lane], v1 = xs[s1 * 5 + lane];
            float v2 = xs[s2 * 5 + lane], v3 = xs[s3 * 5 + lane];
            float v4 = xs[s4 * 5 + lane], v5 = xs[s5 * 5 + lane];
            float v6 = xs[s6 * 5 + lane], v7 = xs[s7 * 5 + lane];
            a0 += v0; a1 += v1; a2 += v2; a3 += v3;
            a0 += v4; a1 += v5; a2 += v6; a3 += v7;
        }
    }
    for (; j < end; ++j) {
        int s = csr[j];
        if (lane < 5) a0 += xs[s * 5 + lane];
    }
    float di = dinv[node];
    float acc = ((a0 + a1) + (a2 + a3)) * di;

    float out = sB[lane];
#pragma unroll
    for (int k = 0; k < 5; ++k) out += __shfl(acc, k, 64) * sW[k * HF + lane];
    out = fmaxf(out, 0.f);
    hout[node * HF + lane] = f32_to_fp8(out * di);   // pre-scale for next layer
}

// ---- layers 2/3 fused: fp8 gather, 8 outstanding loads/wave, @W' (BN-folded), ReLU ----
// SCALE_OUT=1: write fp8 hs = h*dinv. SCALE_OUT=0: write fp32 h (feeds pool).
template <int SCALE_OUT>
__global__ __launch_bounds__(256) void k_layer(
    const unsigned char* __restrict__ hs8, void* __restrict__ hout_v,
    const int* __restrict__ csr, const int* __restrict__ basep,
    const float* __restrict__ dinv,
    const float* __restrict__ W, const float* __restrict__ b,
    const float* __restrict__ g, const float* __restrict__ be,
    const float* __restrict__ rm, const float* __restrict__ rv, int N) {
    __shared__ float sW[HF * HF];
    __shared__ float sB[HF];
    for (int i = threadIdx.x; i < HF * HF; i += blockDim.x) {
        int f = i & (HF - 1);
        sW[i] = W[i] * (g[f] * rsqrtf(rv[f] + EPS));
    }
    if (threadIdx.x < HF) {
        int f = threadIdx.x;
        float scale = g[f] * rsqrtf(rv[f] + EPS);
        sB[f] = (b[f] - rm[f]) * scale + be[f];
    }
    __syncthreads();

    int node = blockIdx.x * (blockDim.x >> 6) + (threadIdx.x >> 6);
    int lane = threadIdx.x & 63;
    if (node >= N) return;

    int j   = __builtin_amdgcn_readfirstlane(basep[node]);
    int end = __builtin_amdgcn_readfirstlane(basep[node + 1]);

    const unsigned char* col = hs8 + lane;   // lane's feature column

    // self term (already *dinv[src])
    float a0 = __builtin_amdgcn_cvt_f32_fp8((unsigned)col[(size_t)node * HF], 0);
    float a1 = 0.f, a2 = 0.f, a3 = 0.f;

    // 8-wide MLP: 8 adjacent scalar index loads, then 8 independent byte-gathers
    for (; j + 8 <= end; j += 8) {
        int s0 = csr[j+0], s1 = csr[j+1], s2 = csr[j+2], s3 = csr[j+3];
        int s4 = csr[j+4], s5 = csr[j+5], s6 = csr[j+6], s7 = csr[j+7];
        unsigned u0 = col[(size_t)s0 * HF];
        unsigned u1 = col[(size_t)s1 * HF];
        unsigned u2 = col[(size_t)s2 * HF];
        unsigned u3 = col[(size_t)s3 * HF];
        unsigned u4 = col[(size_t)s4 * HF];
        unsigned u5 = col[(size_t)s5 * HF];
        unsigned u6 = col[(size_t)s6 * HF];
        unsigned u7 = col[(size_t)s7 * HF];
        a0 += __builtin_amdgcn_cvt_f32_fp8(u0, 0);
        a1 += __builtin_amdgcn_cvt_f32_fp8(u1, 0);
        a2 += __builtin_amdgcn_cvt_f32_fp8(u2, 0);
        a3 += __builtin_amdgcn_cvt_f32_fp8(u3, 0);
        a0 += __builtin_amdgcn_cvt_f32_fp8(u4, 0);
        a1 += __builtin_amdgcn_cvt_f32_fp8(u5, 0);
        a2 += __builtin_amdgcn_cvt_f32_fp8(u6, 0);
        a3 += __builtin_amdgcn_cvt_f32_fp8(u7, 0);
    }
    for (; j < end; ++j) {
        int s = csr[j];
        a0 += __builtin_amdgcn_cvt_f32_fp8((unsigned)col[(size_t)s * HF], 0);
    }
    float di = dinv[node];
    float acc = ((a0 + a1) + (a2 + a3)) * di;

    float out = sB[lane];
#pragma unroll 8
    for (int k = 0; k < HF; ++k) out += __shfl(acc, k, 64) * sW[k * HF + lane];
    out = fmaxf(out, 0.f);
    if (SCALE_OUT) {
        ((unsigned char*)hout_v)[(size_t)node * HF + lane] = f32_to_fp8(out * di);
    } else {
        ((float*)hout_v)[(size_t)node * HF + lane] = out;
    }
}

// ---- per-graph mean-pool + FC(64->32) relu + FC(32->2) sigmoid ----
__global__ void k_pool_fc(const float* __restrict__ h, const int* __restrict__ batch,
                          const float* __restrict__ Wf1, const float* __restrict__ bf1,
                          const float* __restrict__ Wf2, const float* __restrict__ bf2,
                          float* __restrict__ out, int N) {
    int g = blockIdx.x;
    int t = threadIdx.x;
    int f = t & 63, q = t >> 6;

    int lo = 0, hi = N;
    while (lo < hi) { int mid = (lo + hi) >> 1; if (batch[mid] < g) lo = mid + 1; else hi = mid; }
    int start = lo;
    hi = N;
    while (lo < hi) { int mid = (lo + hi) >> 1; if (batch[mid] < g + 1) lo = mid + 1; else hi = mid; }
    int end = lo;

    float sum = 0.f;
    for (int n = start + q; n < end; n += 4) sum += h[n * HF + f];

    __shared__ float red[4][HF];
    __shared__ float sp[HF];
    __shared__ float sh[32];
    red[q][f] = sum;
    __syncthreads();
    if (q == 0) {
        float s = red[0][f] + red[1][f] + red[2][f] + red[3][f];
        float cntf = (float)(end - start);
        sp[f] = s / fmaxf(cntf, 1.0f);
    }
    __syncthreads();
    if (t < 32) {
        float a = bf1[t];
#pragma unroll
        for (int k = 0; k < HF; ++k) a += sp[k] * Wf1[k * 32 + t];
        sh[t] = fmaxf(a, 0.f);
    }
    __syncthreads();
    if (t < 2) {
        float a = bf2[t];
#pragma unroll
        for (int k = 0; k < 32; ++k) a += sh[k] * Wf2[k * 2 + t];
        out[g * 2 + t] = 1.f / (1.f + expf(-a));
    }
}

extern "C" void kernel_launch(void* const* d_in, const int* in_sizes, int n_in,
                              void* d_out, int out_size, void* d_ws, size_t ws_size,
                              hipStream_t stream) {
    const float* x     = (const float*)d_in[0];
    const int*   ei    = (const int*)d_in[1];
    const int*   batch = (const int*)d_in[2];
    const float* W1 = (const float*)d_in[3];
    const float* b1 = (const float*)d_in[4];
    const float* g1 = (const float*)d_in[5];
    const float* be1 = (const float*)d_in[6];
    const float* rm1 = (const float*)d_in[7];
    const float* rv1 = (const float*)d_in[8];
    const float* W2 = (const float*)d_in[9];
    const float* b2 = (const float*)d_in[10];
    const float* g2 = (const float*)d_in[11];
    const float* be2 = (const float*)d_in[12];
    const float* rm2 = (const float*)d_in[13];
    const float* rv2 = (const float*)d_in[14];
    const float* W3 = (const float*)d_in[15];
    const float* b3 = (const float*)d_in[16];
    const float* g3 = (const float*)d_in[17];
    const float* be3 = (const float*)d_in[18];
    const float* rm3 = (const float*)d_in[19];
    const float* rv3 = (const float*)d_in[20];
    const float* Wf1 = (const float*)d_in[21];
    const float* bf1 = (const float*)d_in[22];
    const float* Wf2 = (const float*)d_in[23];
    const float* bf2 = (const float*)d_in[24];
    float* out = (float*)d_out;

    const int N = in_sizes[2];            // 100000
    const int E = in_sizes[1] / 2;        // 3200000
    const int G = out_size / 2;           // 256
    const int B = (N + BKN - 1) / BKN;    // buckets (196)

    char* ws = (char*)d_ws;
    size_t off = 0;
    auto alloc = [&](size_t bytes) {
        char* p = ws + off;
        off += (bytes + 255) & ~(size_t)255;
        return p;
    };
    float*         H3       = (float*)alloc((size_t)N * HF * sizeof(float));
    unsigned char* HS1      = (unsigned char*)alloc((size_t)N * HF);
    unsigned char* HS2      = (unsigned char*)alloc((size_t)N * HF);
    float*         xs       = (float*)alloc((size_t)N * 5 * sizeof(float));
    float*         dinv     = (float*)alloc((size_t)N * sizeof(float));
    int*           cnt      = (int*)  alloc((size_t)N * sizeof(int));
    int*           chunk_sc = (int*)  alloc((size_t)N * sizeof(int));
    int*           base     = (int*)  alloc(((size_t)N + 1) * sizeof(int));
    int*           bcur     = (int*)  alloc((size_t)NBUCK_MAX * sizeof(int));
    int*           bsum     = (int*)  alloc(256 * sizeof(int));
    int*           bbase    = (int*)  alloc(256 * sizeof(int));
    int*           csr      = (int*)  alloc((size_t)E * sizeof(int));
    int*           stage    = (int*)H3;   // alias: consumed (passC) before H3 written (layer 3)

    const int* src = ei;
    const int* dst = ei + E;

    const int BT = 256;
    int gE  = (E + BT - 1) / BT;
    int NB  = (N + SCAN_B - 1) / SCAN_B;
    int gW  = (N + 3) / 4;
    int gP  = (N * 5 + BT - 1) / BT;
    int gPB = (E + PB_TILE - 1) / PB_TILE;

    // ---- CSR build ----
    hipMemsetAsync(cnt, 0, (size_t)N * sizeof(int), stream);
    k_hist<<<gE, BT, 0, stream>>>(cnt, dst, E);
    k_scan1<<<NB, SCAN_B, 0, stream>>>(cnt, chunk_sc, bsum, dinv, N);
    k_scan2<<<1, 64, 0, stream>>>(bsum, bbase, base, NB, N);
    k_scan3<<<NB, SCAN_B, 0, stream>>>(chunk_sc, bbase, base, N);
    k_binit<<<1, 256, 0, stream>>>(base, bcur, B);
    k_passB<<<gPB, PB_T, 0, stream>>>(src, dst, bcur, stage, E, B);
    k_passC<<<B, 512, 0, stream>>>(stage, base, csr, N);
    k_prescale<<<gP, BT, 0, stream>>>(x, dinv, xs, N * 5);

    // ---- fused layers ----
    k_layer1<<<gW, BT, 0, stream>>>(xs, HS1, csr, base, dinv,
                                    W1, b1, g1, be1, rm1, rv1, N);
    k_layer<1><<<gW, BT, 0, stream>>>(HS1, HS2, csr, base, dinv,
                                      W2, b2, g2, be2, rm2, rv2, N);
    k_layer<0><<<gW, BT, 0, stream>>>(HS2, H3, csr, base, dinv,
                                      W3, b3, g3, be3, rm3, rv3, N);

    // ---- pool + MLP head ----
    k_pool_fc<<<G, BT, 0, stream>>>(H3, batch, Wf1, bf1, Wf2, bf2, out, N);
}

// Round 10
// 637.971 us; speedup vs baseline: 1.2601x; 1.1232x over previous
//
#include <hip/hip_runtime.h>
#include <hip/hip_bf16.h>

#define HF 64
#define EPS 1e-5f
#define SCAN_B 1024

#define BSH 9                    // bucket shift: 512 nodes / bucket
#define BKN (1 << BSH)           // 512 nodes per bucket
#define NBUCK_MAX 256            // >= ceil(N / BKN)
#define PB_T 256                 // passB threads
#define PB_EPT 32                // edges per thread
#define PB_TILE (PB_T * PB_EPT)  // 8192 edges per block

#define LGRID 1536               // k_layer grid: ~6 blocks/CU, grid-stride over nodes

typedef __hip_bfloat16 bf16;

__device__ __forceinline__ unsigned char f32_to_fp8(float v) {
    int p = __builtin_amdgcn_cvt_pk_fp8_f32(v, v, 0, false);
    return (unsigned char)(p & 0xff);
}

// ---- histogram of dst (in-degree, excluding self loop) ----
__global__ void k_hist(int* __restrict__ cnt, const int* __restrict__ dst, int E) {
    int e = blockIdx.x * blockDim.x + threadIdx.x;
    if (e < E) atomicAdd(&cnt[dst[e]], 1);
}

// ---- scan stage 1: per-1024-chunk exclusive scan + chunk totals; also dinv ----
__global__ void k_scan1(const int* __restrict__ cnt, int* __restrict__ chunk_scan,
                        int* __restrict__ bsum, float* __restrict__ dinv, int N) {
    __shared__ int tmp[2][SCAN_B];
    int t = threadIdx.x;
    int gid = blockIdx.x * SCAN_B + t;
    int v = (gid < N) ? cnt[gid] : 0;
    if (gid < N) dinv[gid] = rsqrtf((float)v + 1.0f);
    int pi = 0;
    tmp[0][t] = v;
    __syncthreads();
    for (int off = 1; off < SCAN_B; off <<= 1) {
        int val = tmp[pi][t];
        if (t >= off) val += tmp[pi][t - off];
        tmp[pi ^ 1][t] = val;
        pi ^= 1;
        __syncthreads();
    }
    int inc = tmp[pi][t];
    if (gid < N) chunk_scan[gid] = inc - v;
    if (t == SCAN_B - 1) bsum[blockIdx.x] = inc;
}

// ---- scan stage 2: exclusive scan of chunk totals; writes base[N] = E ----
__global__ void k_scan2(const int* __restrict__ bsum, int* __restrict__ bbase,
                        int* __restrict__ base, int NB, int N) {
    if (threadIdx.x == 0 && blockIdx.x == 0) {
        int acc = 0;
        for (int i = 0; i < NB; ++i) { bbase[i] = acc; acc += bsum[i]; }
        base[N] = acc;   // == E
    }
}

// ---- scan stage 3: base = chunk_scan + bbase ----
__global__ void k_scan3(const int* __restrict__ chunk_scan, const int* __restrict__ bbase,
                        int* __restrict__ base, int N) {
    int gid = blockIdx.x * SCAN_B + threadIdx.x;
    if (gid < N) base[gid] = chunk_scan[gid] + bbase[blockIdx.x];
}

// ---- bucket cursor init: bcur[beta] = base[beta*BKN] ----
__global__ void k_binit(const int* __restrict__ base, int* __restrict__ bcur, int B) {
    int b = blockIdx.x * blockDim.x + threadIdx.x;
    if (b < B) bcur[b] = base[b * BKN];
}

// ---- pass B: block-tiled binning; reserve per-(block,bucket) RUNS, write block-private ----
__global__ __launch_bounds__(PB_T) void k_passB(
    const int* __restrict__ src, const int* __restrict__ dst,
    int* __restrict__ bcur, int* __restrict__ stage, int E, int B) {
    __shared__ int scnt[NBUCK_MAX];
    __shared__ int sgoff[NBUCK_MAX];
    int t = threadIdx.x;
    int tile0 = blockIdx.x * PB_TILE;

    for (int b = t; b < B; b += PB_T) scnt[b] = 0;
    __syncthreads();

    int rec[PB_EPT];
    int bkt[PB_EPT];
#pragma unroll
    for (int k = 0; k < PB_EPT; ++k) {
        int e = tile0 + k * PB_T + t;
        bkt[k] = -1;
        if (e < E) {
            int d = dst[e];
            int s = src[e];
            int b = d >> BSH;
            bkt[k] = b;
            rec[k] = s | ((d & (BKN - 1)) << 17);
            atomicAdd(&scnt[b], 1);
        }
    }
    __syncthreads();

    for (int b = t; b < B; b += PB_T) {
        int c = scnt[b];
        sgoff[b] = c ? atomicAdd(&bcur[b], c) : 0;
        scnt[b] = 0;
    }
    __syncthreads();

#pragma unroll
    for (int k = 0; k < PB_EPT; ++k) {
        if (bkt[k] >= 0) {
            int loc = atomicAdd(&scnt[bkt[k]], 1);
            stage[sgoff[bkt[k]] + loc] = rec[k];
        }
    }
}

// ---- pass C: one block per bucket; scatter staged slice into contiguous CSR rows ----
__global__ __launch_bounds__(512) void k_passC(const int* __restrict__ stage,
                                               const int* __restrict__ base,
                                               int* __restrict__ csr, int N) {
    __shared__ int lcur[BKN];
    int beta = blockIdx.x;
    int n0 = beta * BKN;
    int n1 = n0 + BKN; if (n1 > N) n1 = N;
    int t = threadIdx.x;
    if (t < n1 - n0) lcur[t] = base[n0 + t];
    __syncthreads();
    int rbeg = base[n0], rend = base[n1];
    for (int i = rbeg + t; i < rend; i += 512) {
        int r = stage[i];
        int s = r & 0x1ffff;
        int dl = r >> 17;
        int pos = atomicAdd(&lcur[dl], 1);
        csr[pos] = s;
    }
}

// ---- prescale: xs[n,c] = x[n,c] * dinv[n] ----
__global__ void k_prescale(const float* __restrict__ x, const float* __restrict__ dinv,
                           float* __restrict__ xs, int N5) {
    int i = blockIdx.x * blockDim.x + threadIdx.x;
    if (i < N5) xs[i] = x[i] * dinv[i / 5];
}

// ---- layer 1 fused: stage W once/block, grid-stride over nodes ----
__global__ __launch_bounds__(256) void k_layer1(
    const float* __restrict__ xs, unsigned char* __restrict__ hout,
    const int* __restrict__ csr, const int* __restrict__ basep,
    const float* __restrict__ dinv,
    const float* __restrict__ W1, const float* __restrict__ b,
    const float* __restrict__ g, const float* __restrict__ be,
    const float* __restrict__ rm, const float* __restrict__ rv, int N) {
    __shared__ float sW[5 * HF];
    __shared__ float sB[HF];
    __shared__ float sScale[HF];
    if (threadIdx.x < HF) {
        int f = threadIdx.x;
        float scale = g[f] * rsqrtf(rv[f] + EPS);
        sScale[f] = scale;
        sB[f] = (b[f] - rm[f]) * scale + be[f];
    }
    __syncthreads();
    for (int i = threadIdx.x; i < 5 * HF; i += blockDim.x)
        sW[i] = W1[i] * sScale[i & (HF - 1)];
    __syncthreads();

    int lane = threadIdx.x & 63;
    int wave = threadIdx.x >> 6;
    int stride = gridDim.x * 4;

    for (int node = blockIdx.x * 4 + wave; node < N; node += stride) {
        int j   = __builtin_amdgcn_readfirstlane(basep[node]);
        int end = __builtin_amdgcn_readfirstlane(basep[node + 1]);

        float a0 = 0.f, a1 = 0.f, a2 = 0.f, a3 = 0.f;
        if (lane < 5) a0 = xs[node * 5 + lane];   // self term
        for (; j + 8 <= end; j += 8) {
            int s0 = csr[j+0], s1 = csr[j+1], s2 = csr[j+2], s3 = csr[j+3];
            int s4 = csr[j+4], s5 = csr[j+5], s6 = csr[j+6], s7 = csr[j+7];
            if (lane < 5) {
                float v0 = xs[s0 * 5 + lane], v1 = xs[s1 * 5 + lane];
                float v2 = xs[s2 * 5 + lane], v3 = xs[s3 * 5 + lane];
                float v4 = xs[s4 * 5 + lane], v5 = xs[s5 * 5 + lane];
                float v6 = xs[s6 * 5 + lane], v7 = xs[s7 * 5 + lane];
                a0 += v0; a1 += v1; a2 += v2; a3 += v3;
                a0 += v4; a1 += v5; a2 += v6; a3 += v7;
            }
        }
        for (; j < end; ++j) {
            int s = csr[j];
            if (lane < 5) a0 += xs[s * 5 + lane];
        }
        float di = dinv[node];
        float acc = ((a0 + a1) + (a2 + a3)) * di;

        float out = sB[lane];
#pragma unroll
        for (int k = 0; k < 5; ++k) out += __shfl(acc, k, 64) * sW[k * HF + lane];
        out = fmaxf(out, 0.f);
        hout[(size_t)node * HF + lane] = f32_to_fp8(out * di);  // pre-scale for next layer
    }
}

// ---- layers 2/3 fused: stage folded W once/block, grid-stride over nodes ----
// SCALE_OUT=1: write fp8 hs = h*dinv. SCALE_OUT=0: write fp32 h (feeds pool).
template <int SCALE_OUT>
__global__ __launch_bounds__(256) void k_layer(
    const unsigned char* __restrict__ hs8, void* __restrict__ hout_v,
    const int* __restrict__ csr, const int* __restrict__ basep,
    const float* __restrict__ dinv,
    const float* __restrict__ W, const float* __restrict__ b,
    const float* __restrict__ g, const float* __restrict__ be,
    const float* __restrict__ rm, const float* __restrict__ rv, int N) {
    __shared__ float sW[HF * HF];
    __shared__ float sB[HF];
    __shared__ float sScale[HF];
    if (threadIdx.x < HF) {
        int f = threadIdx.x;
        float scale = g[f] * rsqrtf(rv[f] + EPS);
        sScale[f] = scale;
        sB[f] = (b[f] - rm[f]) * scale + be[f];
    }
    __syncthreads();
    for (int i = threadIdx.x; i < HF * HF; i += blockDim.x)
        sW[i] = W[i] * sScale[i & (HF - 1)];
    __syncthreads();

    int lane = threadIdx.x & 63;
    int wave = threadIdx.x >> 6;
    int stride = gridDim.x * 4;
    const unsigned char* col = hs8 + lane;   // lane's feature column

    for (int node = blockIdx.x * 4 + wave; node < N; node += stride) {
        int j   = __builtin_amdgcn_readfirstlane(basep[node]);
        int end = __builtin_amdgcn_readfirstlane(basep[node + 1]);

        // self term (already *dinv[src])
        float a0 = __builtin_amdgcn_cvt_f32_fp8((unsigned)col[(size_t)node * HF], 0);
        float a1 = 0.f, a2 = 0.f, a3 = 0.f;

        // 8-wide MLP: 8 adjacent scalar index loads, then 8 independent byte-gathers
        for (; j + 8 <= end; j += 8) {
            int s0 = csr[j+0], s1 = csr[j+1], s2 = csr[j+2], s3 = csr[j+3];
            int s4 = csr[j+4], s5 = csr[j+5], s6 = csr[j+6], s7 = csr[j+7];
            unsigned u0 = col[(size_t)s0 * HF];
            unsigned u1 = col[(size_t)s1 * HF];
            unsigned u2 = col[(size_t)s2 * HF];
            unsigned u3 = col[(size_t)s3 * HF];
            unsigned u4 = col[(size_t)s4 * HF];
            unsigned u5 = col[(size_t)s5 * HF];
            unsigned u6 = col[(size_t)s6 * HF];
            unsigned u7 = col[(size_t)s7 * HF];
            a0 += __builtin_amdgcn_cvt_f32_fp8(u0, 0);
            a1 += __builtin_amdgcn_cvt_f32_fp8(u1, 0);
            a2 += __builtin_amdgcn_cvt_f32_fp8(u2, 0);
            a3 += __builtin_amdgcn_cvt_f32_fp8(u3, 0);
            a0 += __builtin_amdgcn_cvt_f32_fp8(u4, 0);
            a1 += __builtin_amdgcn_cvt_f32_fp8(u5, 0);
            a2 += __builtin_amdgcn_cvt_f32_fp8(u6, 0);
            a3 += __builtin_amdgcn_cvt_f32_fp8(u7, 0);
        }
        for (; j < end; ++j) {
            int s = csr[j];
            a0 += __builtin_amdgcn_cvt_f32_fp8((unsigned)col[(size_t)s * HF], 0);
        }
        float di = dinv[node];
        float acc = ((a0 + a1) + (a2 + a3)) * di;

        float out = sB[lane];
#pragma unroll 8
        for (int k = 0; k < HF; ++k) out += __shfl(acc, k, 64) * sW[k * HF + lane];
        out = fmaxf(out, 0.f);
        if (SCALE_OUT) {
            ((unsigned char*)hout_v)[(size_t)node * HF + lane] = f32_to_fp8(out * di);
        } else {
            ((float*)hout_v)[(size_t)node * HF + lane] = out;
        }
    }
}

// ---- per-graph mean-pool + FC(64->32) relu + FC(32->2) sigmoid ----
__global__ void k_pool_fc(const float* __restrict__ h, const int* __restrict__ batch,
                          const float* __restrict__ Wf1, const float* __restrict__ bf1,
                          const float* __restrict__ Wf2, const float* __restrict__ bf2,
                          float* __restrict__ out, int N) {
    int g = blockIdx.x;
    int t = threadIdx.x;
    int f = t & 63, q = t >> 6;

    int lo = 0, hi = N;
    while (lo < hi) { int mid = (lo + hi) >> 1; if (batch[mid] < g) lo = mid + 1; else hi = mid; }
    int start = lo;
    hi = N;
    while (lo < hi) { int mid = (lo + hi) >> 1; if (batch[mid] < g + 1) lo = mid + 1; else hi = mid; }
    int end = lo;

    float sum = 0.f;
    for (int n = start + q; n < end; n += 4) sum += h[n * HF + f];

    __shared__ float red[4][HF];
    __shared__ float sp[HF];
    __shared__ float sh[32];
    red[q][f] = sum;
    __syncthreads();
    if (q == 0) {
        float s = red[0][f] + red[1][f] + red[2][f] + red[3][f];
        float cntf = (float)(end - start);
        sp[f] = s / fmaxf(cntf, 1.0f);
    }
    __syncthreads();
    if (t < 32) {
        float a = bf1[t];
#pragma unroll
        for (int k = 0; k < HF; ++k) a += sp[k] * Wf1[k * 32 + t];
        sh[t] = fmaxf(a, 0.f);
    }
    __syncthreads();
    if (t < 2) {
        float a = bf2[t];
#pragma unroll
        for (int k = 0; k < 32; ++k) a += sh[k] * Wf2[k * 2 + t];
        out[g * 2 + t] = 1.f / (1.f + expf(-a));
    }
}

extern "C" void kernel_launch(void* const* d_in, const int* in_sizes, int n_in,
                              void* d_out, int out_size, void* d_ws, size_t ws_size,
                              hipStream_t stream) {
    const float* x     = (const float*)d_in[0];
    const int*   ei    = (const int*)d_in[1];
    const int*   batch = (const int*)d_in[2];
    const float* W1 = (const float*)d_in[3];
    const float* b1 = (const float*)d_in[4];
    const float* g1 = (const float*)d_in[5];
    const float* be1 = (const float*)d_in[6];
    const float* rm1 = (const float*)d_in[7];
    const float* rv1 = (const float*)d_in[8];
    const float* W2 = (const float*)d_in[9];
    const float* b2 = (const float*)d_in[10];
    const float* g2 = (const float*)d_in[11];
    const float* be2 = (const float*)d_in[12];
    const float* rm2 = (const float*)d_in[13];
    const float* rv2 = (const float*)d_in[14];
    const float* W3 = (const float*)d_in[15];
    const float* b3 = (const float*)d_in[16];
    const float* g3 = (const float*)d_in[17];
    const float* be3 = (const float*)d_in[18];
    const float* rm3 = (const float*)d_in[19];
    const float* rv3 = (const float*)d_in[20];
    const float* Wf1 = (const float*)d_in[21];
    const float* bf1 = (const float*)d_in[22];
    const float* Wf2 = (const float*)d_in[23];
    const float* bf2 = (const float*)d_in[24];
    float* out = (float*)d_out;

    const int N = in_sizes[2];            // 100000
    const int E = in_sizes[1] / 2;        // 3200000
    const int G = out_size / 2;           // 256
    const int B = (N + BKN - 1) / BKN;    // buckets (196)

    char* ws = (char*)d_ws;
    size_t off = 0;
    auto alloc = [&](size_t bytes) {
        char* p = ws + off;
        off += (bytes + 255) & ~(size_t)255;
        return p;
    };
    float*         H3       = (float*)alloc((size_t)N * HF * sizeof(float));
    unsigned char* HS1      = (unsigned char*)alloc((size_t)N * HF);
    unsigned char* HS2      = (unsigned char*)alloc((size_t)N * HF);
    float*         xs       = (float*)alloc((size_t)N * 5 * sizeof(float));
    float*         dinv     = (float*)alloc((size_t)N * sizeof(float));
    int*           cnt      = (int*)  alloc((size_t)N * sizeof(int));
    int*           chunk_sc = (int*)  alloc((size_t)N * sizeof(int));
    int*           base     = (int*)  alloc(((size_t)N + 1) * sizeof(int));
    int*           bcur     = (int*)  alloc((size_t)NBUCK_MAX * sizeof(int));
    int*           bsum     = (int*)  alloc(256 * sizeof(int));
    int*           bbase    = (int*)  alloc(256 * sizeof(int));
    int*           csr      = (int*)  alloc((size_t)E * sizeof(int));
    int*           stage    = (int*)H3;   // alias: consumed (passC) before H3 written (layer 3)

    const int* src = ei;
    const int* dst = ei + E;

    const int BT = 256;
    int gE  = (E + BT - 1) / BT;
    int NB  = (N + SCAN_B - 1) / SCAN_B;
    int gP  = (N * 5 + BT - 1) / BT;
    int gPB = (E + PB_TILE - 1) / PB_TILE;

    // ---- CSR build ----
    hipMemsetAsync(cnt, 0, (size_t)N * sizeof(int), stream);
    k_hist<<<gE, BT, 0, stream>>>(cnt, dst, E);
    k_scan1<<<NB, SCAN_B, 0, stream>>>(cnt, chunk_sc, bsum, dinv, N);
    k_scan2<<<1, 64, 0, stream>>>(bsum, bbase, base, NB, N);
    k_scan3<<<NB, SCAN_B, 0, stream>>>(chunk_sc, bbase, base, N);
    k_binit<<<1, 256, 0, stream>>>(base, bcur, B);
    k_passB<<<gPB, PB_T, 0, stream>>>(src, dst, bcur, stage, E, B);
    k_passC<<<B, 512, 0, stream>>>(stage, base, csr, N);
    k_prescale<<<gP, BT, 0, stream>>>(x, dinv, xs, N * 5);

    // ---- fused layers (weights staged once per block; grid-stride over nodes) ----
    k_layer1<<<LGRID, BT, 0, stream>>>(xs, HS1, csr, base, dinv,
                                       W1, b1, g1, be1, rm1, rv1, N);
    k_layer<1><<<LGRID, BT, 0, stream>>>(HS1, HS2, csr, base, dinv,
                                         W2, b2, g2, be2, rm2, rv2, N);
    k_layer<0><<<LGRID, BT, 0, stream>>>(HS2, H3, csr, base, dinv,
                                         W3, b3, g3, be3, rm3, rv3, N);

    // ---- pool + MLP head ----
    k_pool_fc<<<G, BT, 0, stream>>>(H3, batch, Wf1, bf1, Wf2, bf2, out, N);
}

// Round 11
// 530.976 us; speedup vs baseline: 1.5140x; 1.2015x over previous
//
#include <hip/hip_runtime.h>
#include <hip/hip_bf16.h>

#define HF 64
#define EPS 1e-5f

#define BSH 9                    // bucket shift: 512 nodes / bucket
#define BKN (1 << BSH)           // 512 nodes per bucket
#define NBUCK_MAX 256            // >= ceil(N / BKN)
#define PB_T 256                 // passB threads
#define PB_EPT 32                // edges per thread
#define PB_TILE (PB_T * PB_EPT)  // 8192 edges per block

#define LGRID 1536               // k_layer grid: ~6 blocks/CU, grid-stride over nodes

typedef __hip_bfloat16 bf16;

__device__ __forceinline__ unsigned char f32_to_fp8(float v) {
    int p = __builtin_amdgcn_cvt_pk_fp8_f32(v, v, 0, false);
    return (unsigned char)(p & 0xff);
}

// ---- bucket histogram: LDS per-block, one global atomic per (block,bucket) ----
__global__ __launch_bounds__(PB_T) void k_bhist(const int* __restrict__ dst,
                                                int* __restrict__ bcnt, int E, int B) {
    __shared__ int bh[NBUCK_MAX];
    int t = threadIdx.x;
    for (int b = t; b < B; b += PB_T) bh[b] = 0;
    __syncthreads();
    int tile0 = blockIdx.x * PB_TILE;
#pragma unroll
    for (int k = 0; k < PB_EPT; ++k) {
        int e = tile0 + k * PB_T + t;
        if (e < E) atomicAdd(&bh[dst[e] >> BSH], 1);
    }
    __syncthreads();
    for (int b = t; b < B; b += PB_T) {
        int c = bh[b];
        if (c) atomicAdd(&bcnt[b], c);
    }
}

// ---- bucket scan: bbase2 = excl scan(bcnt); bcur = bbase2; base[N] = E ----
__global__ void k_bscan(const int* __restrict__ bcnt, int* __restrict__ bbase2,
                        int* __restrict__ bcur, int* __restrict__ base, int B, int N, int E) {
    if (threadIdx.x == 0 && blockIdx.x == 0) {
        int acc = 0;
        for (int i = 0; i < B; ++i) { bbase2[i] = acc; bcur[i] = acc; acc += bcnt[i]; }
        bbase2[B] = acc;   // == E
        base[N] = E;
    }
}

// ---- pass B: block-tiled binning; reserve per-(block,bucket) RUNS, write block-private ----
__global__ __launch_bounds__(PB_T) void k_passB(
    const int* __restrict__ src, const int* __restrict__ dst,
    int* __restrict__ bcur, int* __restrict__ stage, int E, int B) {
    __shared__ int scnt[NBUCK_MAX];
    __shared__ int sgoff[NBUCK_MAX];
    int t = threadIdx.x;
    int tile0 = blockIdx.x * PB_TILE;

    for (int b = t; b < B; b += PB_T) scnt[b] = 0;
    __syncthreads();

    int rec[PB_EPT];
    int bkt[PB_EPT];
#pragma unroll
    for (int k = 0; k < PB_EPT; ++k) {
        int e = tile0 + k * PB_T + t;
        bkt[k] = -1;
        if (e < E) {
            int d = dst[e];
            int s = src[e];
            int b = d >> BSH;
            bkt[k] = b;
            rec[k] = s | ((d & (BKN - 1)) << 17);
            atomicAdd(&scnt[b], 1);
        }
    }
    __syncthreads();

    for (int b = t; b < B; b += PB_T) {
        int c = scnt[b];
        sgoff[b] = c ? atomicAdd(&bcur[b], c) : 0;
        scnt[b] = 0;
    }
    __syncthreads();

#pragma unroll
    for (int k = 0; k < PB_EPT; ++k) {
        if (bkt[k] >= 0) {
            int loc = atomicAdd(&scnt[bkt[k]], 1);
            stage[sgoff[bkt[k]] + loc] = rec[k];
        }
    }
}

// ---- pass C: per bucket: LDS node-hist -> scan -> base/dinv -> scatter csr ----
__global__ __launch_bounds__(512) void k_passC(const int* __restrict__ stage,
                                               const int* __restrict__ bb2,
                                               int* __restrict__ base,
                                               float* __restrict__ dinv,
                                               int* __restrict__ csr, int N) {
    __shared__ int lcnt[BKN];
    __shared__ int lscan[BKN];
    __shared__ int lcur[BKN];
    int beta = blockIdx.x;
    int n0 = beta * BKN;
    int n1 = n0 + BKN; if (n1 > N) n1 = N;
    int nn = n1 - n0;
    int t = threadIdx.x;       // blockDim == 512 == BKN
    lcnt[t] = 0;
    __syncthreads();
    int rbeg = bb2[beta], rend = bb2[beta + 1];
    for (int i = rbeg + t; i < rend; i += 512)
        atomicAdd(&lcnt[stage[i] >> 17], 1);
    __syncthreads();
    int v = lcnt[t];
    lscan[t] = v;
    __syncthreads();
    for (int off = 1; off < 512; off <<= 1) {
        int val = lscan[t];
        int add = (t >= off) ? lscan[t - off] : 0;
        __syncthreads();
        lscan[t] = val + add;
        __syncthreads();
    }
    int b = rbeg + lscan[t] - v;   // exclusive scan + bucket start
    if (t < nn) {
        base[n0 + t] = b;
        dinv[n0 + t] = rsqrtf((float)v + 1.0f);
    }
    lcur[t] = b;
    __syncthreads();
    for (int i = rbeg + t; i < rend; i += 512) {
        int r = stage[i];
        int pos = atomicAdd(&lcur[r >> 17], 1);
        csr[pos] = r & 0x1ffff;
    }
}

// ---- prescale: xs[n,c] = x[n,c] * dinv[n] ----
__global__ void k_prescale(const float* __restrict__ x, const float* __restrict__ dinv,
                           float* __restrict__ xs, int N5) {
    int i = blockIdx.x * blockDim.x + threadIdx.x;
    if (i < N5) xs[i] = x[i] * dinv[i / 5];
}

// ---- layer 1 fused: stage W once/block, grid-stride over nodes ----
__global__ __launch_bounds__(256) void k_layer1(
    const float* __restrict__ xs, unsigned char* __restrict__ hout,
    const int* __restrict__ csr, const int* __restrict__ basep,
    const float* __restrict__ dinv,
    const float* __restrict__ W1, const float* __restrict__ b,
    const float* __restrict__ g, const float* __restrict__ be,
    const float* __restrict__ rm, const float* __restrict__ rv, int N) {
    __shared__ float sW[5 * HF];
    __shared__ float sB[HF];
    __shared__ float sScale[HF];
    if (threadIdx.x < HF) {
        int f = threadIdx.x;
        float scale = g[f] * rsqrtf(rv[f] + EPS);
        sScale[f] = scale;
        sB[f] = (b[f] - rm[f]) * scale + be[f];
    }
    __syncthreads();
    for (int i = threadIdx.x; i < 5 * HF; i += blockDim.x)
        sW[i] = W1[i] * sScale[i & (HF - 1)];
    __syncthreads();

    int lane = threadIdx.x & 63;
    int wave = threadIdx.x >> 6;
    int stride = gridDim.x * 4;

    for (int node = blockIdx.x * 4 + wave; node < N; node += stride) {
        int j   = __builtin_amdgcn_readfirstlane(basep[node]);
        int end = __builtin_amdgcn_readfirstlane(basep[node + 1]);

        float a0 = 0.f, a1 = 0.f, a2 = 0.f, a3 = 0.f;
        if (lane < 5) a0 = xs[node * 5 + lane];   // self term
        for (; j + 8 <= end; j += 8) {
            int s0 = csr[j+0], s1 = csr[j+1], s2 = csr[j+2], s3 = csr[j+3];
            int s4 = csr[j+4], s5 = csr[j+5], s6 = csr[j+6], s7 = csr[j+7];
            if (lane < 5) {
                float v0 = xs[s0 * 5 + lane], v1 = xs[s1 * 5 + lane];
                float v2 = xs[s2 * 5 + lane], v3 = xs[s3 * 5 + lane];
                float v4 = xs[s4 * 5 + lane], v5 = xs[s5 * 5 + lane];
                float v6 = xs[s6 * 5 + lane], v7 = xs[s7 * 5 + lane];
                a0 += v0; a1 += v1; a2 += v2; a3 += v3;
                a0 += v4; a1 += v5; a2 += v6; a3 += v7;
            }
        }
        for (; j < end; ++j) {
            int s = csr[j];
            if (lane < 5) a0 += xs[s * 5 + lane];
        }
        float di = dinv[node];
        float acc = ((a0 + a1) + (a2 + a3)) * di;

        float out = sB[lane];
#pragma unroll
        for (int k = 0; k < 5; ++k) out += __shfl(acc, k, 64) * sW[k * HF + lane];
        out = fmaxf(out, 0.f);
        hout[(size_t)node * HF + lane] = f32_to_fp8(out * di);  // pre-scale for next layer
    }
}

// ---- layers 2/3 fused: stage folded W once/block, grid-stride over nodes ----
// SCALE_OUT=1: write fp8 hs = h*dinv. SCALE_OUT=0: write fp32 h (feeds pool).
template <int SCALE_OUT>
__global__ __launch_bounds__(256) void k_layer(
    const unsigned char* __restrict__ hs8, void* __restrict__ hout_v,
    const int* __restrict__ csr, const int* __restrict__ basep,
    const float* __restrict__ dinv,
    const float* __restrict__ W, const float* __restrict__ b,
    const float* __restrict__ g, const float* __restrict__ be,
    const float* __restrict__ rm, const float* __restrict__ rv, int N) {
    __shared__ float sW[HF * HF];
    __shared__ float sB[HF];
    __shared__ float sScale[HF];
    if (threadIdx.x < HF) {
        int f = threadIdx.x;
        float scale = g[f] * rsqrtf(rv[f] + EPS);
        sScale[f] = scale;
        sB[f] = (b[f] - rm[f]) * scale + be[f];
    }
    __syncthreads();
    for (int i = threadIdx.x; i < HF * HF; i += blockDim.x)
        sW[i] = W[i] * sScale[i & (HF - 1)];
    __syncthreads();

    int lane = threadIdx.x & 63;
    int wave = threadIdx.x >> 6;
    int stride = gridDim.x * 4;
    const unsigned char* col = hs8 + lane;   // lane's feature column

    for (int node = blockIdx.x * 4 + wave; node < N; node += stride) {
        int j   = __builtin_amdgcn_readfirstlane(basep[node]);
        int end = __builtin_amdgcn_readfirstlane(basep[node + 1]);

        // self term (already *dinv[src])
        float a0 = __builtin_amdgcn_cvt_f32_fp8((unsigned)col[(size_t)node * HF], 0);
        float a1 = 0.f, a2 = 0.f, a3 = 0.f;

        // 8-wide MLP: 8 adjacent scalar index loads, then 8 independent byte-gathers
        for (; j + 8 <= end; j += 8) {
            int s0 = csr[j+0], s1 = csr[j+1], s2 = csr[j+2], s3 = csr[j+3];
            int s4 = csr[j+4], s5 = csr[j+5], s6 = csr[j+6], s7 = csr[j+7];
            unsigned u0 = col[(size_t)s0 * HF];
            unsigned u1 = col[(size_t)s1 * HF];
            unsigned u2 = col[(size_t)s2 * HF];
            unsigned u3 = col[(size_t)s3 * HF];
            unsigned u4 = col[(size_t)s4 * HF];
            unsigned u5 = col[(size_t)s5 * HF];
            unsigned u6 = col[(size_t)s6 * HF];
            unsigned u7 = col[(size_t)s7 * HF];
            a0 += __builtin_amdgcn_cvt_f32_fp8(u0, 0);
            a1 += __builtin_amdgcn_cvt_f32_fp8(u1, 0);
            a2 += __builtin_amdgcn_cvt_f32_fp8(u2, 0);
            a3 += __builtin_amdgcn_cvt_f32_fp8(u3, 0);
            a0 += __builtin_amdgcn_cvt_f32_fp8(u4, 0);
            a1 += __builtin_amdgcn_cvt_f32_fp8(u5, 0);
            a2 += __builtin_amdgcn_cvt_f32_fp8(u6, 0);
            a3 += __builtin_amdgcn_cvt_f32_fp8(u7, 0);
        }
        for (; j < end; ++j) {
            int s = csr[j];
            a0 += __builtin_amdgcn_cvt_f32_fp8((unsigned)col[(size_t)s * HF], 0);
        }
        float di = dinv[node];
        float acc = ((a0 + a1) + (a2 + a3)) * di;

        float out = sB[lane];
#pragma unroll 8
        for (int k = 0; k < HF; ++k) out += __shfl(acc, k, 64) * sW[k * HF + lane];
        out = fmaxf(out, 0.f);
        if (SCALE_OUT) {
            ((unsigned char*)hout_v)[(size_t)node * HF + lane] = f32_to_fp8(out * di);
        } else {
            ((float*)hout_v)[(size_t)node * HF + lane] = out;
        }
    }
}

// ---- per-graph mean-pool + FC(64->32) relu + FC(32->2) sigmoid ----
__global__ void k_pool_fc(const float* __restrict__ h, const int* __restrict__ batch,
                          const float* __restrict__ Wf1, const float* __restrict__ bf1,
                          const float* __restrict__ Wf2, const float* __restrict__ bf2,
                          float* __restrict__ out, int N) {
    int g = blockIdx.x;
    int t = threadIdx.x;
    int f = t & 63, q = t >> 6;

    int lo = 0, hi = N;
    while (lo < hi) { int mid = (lo + hi) >> 1; if (batch[mid] < g) lo = mid + 1; else hi = mid; }
    int start = lo;
    hi = N;
    while (lo < hi) { int mid = (lo + hi) >> 1; if (batch[mid] < g + 1) lo = mid + 1; else hi = mid; }
    int end = lo;

    float sum = 0.f;
    for (int n = start + q; n < end; n += 4) sum += h[n * HF + f];

    __shared__ float red[4][HF];
    __shared__ float sp[HF];
    __shared__ float sh[32];
    red[q][f] = sum;
    __syncthreads();
    if (q == 0) {
        float s = red[0][f] + red[1][f] + red[2][f] + red[3][f];
        float cntf = (float)(end - start);
        sp[f] = s / fmaxf(cntf, 1.0f);
    }
    __syncthreads();
    if (t < 32) {
        float a = bf1[t];
#pragma unroll
        for (int k = 0; k < HF; ++k) a += sp[k] * Wf1[k * 32 + t];
        sh[t] = fmaxf(a, 0.f);
    }
    __syncthreads();
    if (t < 2) {
        float a = bf2[t];
#pragma unroll
        for (int k = 0; k < 32; ++k) a += sh[k] * Wf2[k * 2 + t];
        out[g * 2 + t] = 1.f / (1.f + expf(-a));
    }
}

extern "C" void kernel_launch(void* const* d_in, const int* in_sizes, int n_in,
                              void* d_out, int out_size, void* d_ws, size_t ws_size,
                              hipStream_t stream) {
    const float* x     = (const float*)d_in[0];
    const int*   ei    = (const int*)d_in[1];
    const int*   batch = (const int*)d_in[2];
    const float* W1 = (const float*)d_in[3];
    const float* b1 = (const float*)d_in[4];
    const float* g1 = (const float*)d_in[5];
    const float* be1 = (const float*)d_in[6];
    const float* rm1 = (const float*)d_in[7];
    const float* rv1 = (const float*)d_in[8];
    const float* W2 = (const float*)d_in[9];
    const float* b2 = (const float*)d_in[10];
    const float* g2 = (const float*)d_in[11];
    const float* be2 = (const float*)d_in[12];
    const float* rm2 = (const float*)d_in[13];
    const float* rv2 = (const float*)d_in[14];
    const float* W3 = (const float*)d_in[15];
    const float* b3 = (const float*)d_in[16];
    const float* g3 = (const float*)d_in[17];
    const float* be3 = (const float*)d_in[18];
    const float* rm3 = (const float*)d_in[19];
    const float* rv3 = (const float*)d_in[20];
    const float* Wf1 = (const float*)d_in[21];
    const float* bf1 = (const float*)d_in[22];
    const float* Wf2 = (const float*)d_in[23];
    const float* bf2 = (const float*)d_in[24];
    float* out = (float*)d_out;

    const int N = in_sizes[2];            // 100000
    const int E = in_sizes[1] / 2;        // 3200000
    const int G = out_size / 2;           // 256
    const int B = (N + BKN - 1) / BKN;    // buckets (196)

    char* ws = (char*)d_ws;
    size_t off = 0;
    auto alloc = [&](size_t bytes) {
        char* p = ws + off;
        off += (bytes + 255) & ~(size_t)255;
        return p;
    };
    float*         H3       = (float*)alloc((size_t)N * HF * sizeof(float));
    unsigned char* HS1      = (unsigned char*)alloc((size_t)N * HF);
    unsigned char* HS2      = (unsigned char*)alloc((size_t)N * HF);
    float*         xs       = (float*)alloc((size_t)N * 5 * sizeof(float));
    float*         dinv     = (float*)alloc((size_t)N * sizeof(float));
    int*           base     = (int*)  alloc(((size_t)N + 1) * sizeof(int));
    int*           bcnt     = (int*)  alloc((size_t)NBUCK_MAX * sizeof(int));
    int*           bbase2   = (int*)  alloc(((size_t)NBUCK_MAX + 1) * sizeof(int));
    int*           bcur     = (int*)  alloc((size_t)NBUCK_MAX * sizeof(int));
    int*           csr      = (int*)  alloc((size_t)E * sizeof(int));
    int*           stage    = (int*)H3;   // alias: consumed (passC) before H3 written (layer 3)

    const int* src = ei;
    const int* dst = ei + E;

    const int BT = 256;
    int gP  = (N * 5 + BT - 1) / BT;
    int gPB = (E + PB_TILE - 1) / PB_TILE;

    // ---- CSR build: bucket hist -> 196-scan -> run-reserving partition -> local scatter ----
    hipMemsetAsync(bcnt, 0, (size_t)B * sizeof(int), stream);
    k_bhist<<<gPB, PB_T, 0, stream>>>(dst, bcnt, E, B);
    k_bscan<<<1, 64, 0, stream>>>(bcnt, bbase2, bcur, base, B, N, E);
    k_passB<<<gPB, PB_T, 0, stream>>>(src, dst, bcur, stage, E, B);
    k_passC<<<B, 512, 0, stream>>>(stage, bbase2, base, dinv, csr, N);
    k_prescale<<<gP, BT, 0, stream>>>(x, dinv, xs, N * 5);

    // ---- fused layers (weights staged once per block; grid-stride over nodes) ----
    k_layer1<<<LGRID, BT, 0, stream>>>(xs, HS1, csr, base, dinv,
                                       W1, b1, g1, be1, rm1, rv1, N);
    k_layer<1><<<LGRID, BT, 0, stream>>>(HS1, HS2, csr, base, dinv,
                                         W2, b2, g2, be2, rm2, rv2, N);
    k_layer<0><<<LGRID, BT, 0, stream>>>(HS2, H3, csr, base, dinv,
                                         W3, b3, g3, be3, rm3, rv3, N);

    // ---- pool + MLP head ----
    k_pool_fc<<<G, BT, 0, stream>>>(H3, batch, Wf1, bf1, Wf2, bf2, out, N);
}